// Round 5
// baseline (164.710 us; speedup 1.0000x reference)
//
#include <hip/hip_runtime.h>

#define N_NODES 100000
#define N_EDGES 1600000
#define F 16

// 512 edges per block: 4 waves x 4 iterations x 32 edges. 1.6M/512 = 3125 blocks.
#define EDGES_PER_BLOCK 512
#define ITERS 4

#define OUT_FLOAT4 ((N_NODES * F) / 4)   // 400000

typedef __attribute__((ext_vector_type(8))) short bf16x8;  // 8 bf16 (4 VGPRs)
typedef __attribute__((ext_vector_type(4))) float f32x4;   // MFMA C/D

__global__ __launch_bounds__(256) void zero_out_kernel(float4* __restrict__ out) {
    int i = blockIdx.x * 256 + threadIdx.x;
    if (i < OUT_FLOAT4) out[i] = make_float4(0.f, 0.f, 0.f, 0.f);
}

// pack two f32 -> one dword of 2 bf16 (RNE), single instruction.
__device__ __forceinline__ unsigned pk_bf16(float lo, float hi) {
    unsigned r;
    asm("v_cvt_pk_bf16_f32 %0, %1, %2" : "=v"(r) : "v"(lo), "v"(hi));
    return r;
}

// Round-4 post-mortem: 2 TB/s sustained == hbm_bytes/dur, with every pipe idle
// -> concurrency-limited (Little's law: ~1.5 MB in flight predicts exactly
// 2 TB/s at 600 ns latency). Occupancy is reg-capped (~4 waves/SIMD: 32-reg
// B-fragments + pipeline state ~= 128). Fix: 2x MLP per wave — 32 edges per
// iteration (two 16-edge MFMA units, 4 independent chains), pipeline depth
// per operand class re-balanced to stay under 128 regs:
//   col/attr 2-deep, x 1-deep, r4 0-deep (oldest vmcnt entry -> waiting on it
//   before the atomics does not drain the younger prefetches).
__global__ __launch_bounds__(256, 4) void basis_conv_mfma(
    const float* __restrict__ x,          // [N_NODES, 16]
    const int*   __restrict__ edge_index, // [2, N_EDGES] (int32 on device)
    const float* __restrict__ edge_attr,  // [N_EDGES, 2]
    const float* __restrict__ weight,     // [4,4,16,16] = [cell][i][f]
    float*       __restrict__ out)        // [N_NODES, 16], pre-zeroed
{
    const int lane = threadIdx.x & 63;
    const int wid  = threadIdx.x >> 6;
    const int e15  = lane & 15;        // A-row: edge within 16-edge unit
    const int fo   = lane & 15;        // B/D col: output feature
    const int c    = lane >> 4;        // K-chunk 0..3 within each MFMA
    const int hv   = c >> 1;           // 0: even cell of the pair, 1: odd cell
    const int i0   = (c & 1) * 8;      // input-feature offset within cell

    // --- B fragments (weights), loaded once. MFMA m covers cells 2m, 2m+1.
    bf16x8 bw[8];
#pragma unroll
    for (int m = 0; m < 8; ++m) {
        const float* wp = weight + (2 * m + hv) * 256 + i0 * 16 + fo;
        union { bf16x8 v; unsigned w[4]; } bb;
#pragma unroll
        for (int p = 0; p < 4; ++p)
            bb.w[p] = pk_bf16(wp[(2 * p) * 16], wp[(2 * p + 1) * 16]);
        bw[m] = bb.v;
    }

    const int wbase = blockIdx.x * EDGES_PER_BLOCK + wid * (32 * ITERS);

    // ---- pipeline state ----
    float2 at0[2], at1[2];     // attrs: current iter, next iter
    int    col1[2];            // src node ids for NEXT iter's x prefetch
    float4 xa0[2], xb0[2];     // x operands for current iter

    {
#pragma unroll
        for (int u = 0; u < 2; ++u) {
            const int egA = wbase + u * 16;            // iter 0
            const int col0 = edge_index[N_EDGES + egA + e15];
            at0[u] = ((const float2*)edge_attr)[egA + e15];
            const float4* xv = (const float4*)(x + (size_t)col0 * 16 + i0);
            xa0[u] = xv[0]; xb0[u] = xv[1];
            const int egB = wbase + 32 + u * 16;       // iter 1 (< N_EDGES always)
            col1[u] = edge_index[N_EDGES + egB + e15];
            at1[u]  = ((const float2*)edge_attr)[egB + e15];
        }
    }

#pragma unroll 1
    for (int g = 0; g < ITERS; ++g) {
        // r4 for CURRENT iter: issued first (oldest vmcnt), consumed after the
        // whole compute phase -> latency fully covered, no prefetch regs spent.
        int4 r40[2];
#pragma unroll
        for (int u = 0; u < 2; ++u)
            r40[u] = *(const int4*)(edge_index + (wbase + g * 32 + u * 16) + 4 * c);

        // x prefetch for iter g+1 (cols already resident)
        float4 xa1[2], xb1[2];
#pragma unroll
        for (int u = 0; u < 2; ++u) {
            const float4* xv = (const float4*)(x + (size_t)col1[u] * 16 + i0);
            xa1[u] = xv[0]; xb1[u] = xv[1];
        }

        // meta prefetch for iter g+2 (clamped: reads valid neighbor edges,
        // results unused on the last iterations)
        int col2[2]; float2 at2[2];
#pragma unroll
        for (int u = 0; u < 2; ++u) {
            int eg2 = wbase + (g + 2) * 32 + u * 16;
            eg2 = eg2 > (N_EDGES - 16) ? (N_EDGES - 16) : eg2;
            col2[u] = edge_index[N_EDGES + eg2 + e15];
            at2[u]  = ((const float2*)edge_attr)[eg2 + e15];
        }

        // ---- basis factors for both units ----
        float bu_[2][4], bvE_[2], bvO_[2];
#pragma unroll
        for (int u = 0; u < 2; ++u) {
            float fu = (at0[u].x + 1.0f) * 1.5f;
            int iu = (int)fu; iu = iu < 0 ? 0 : (iu > 2 ? 2 : iu);
            const float wu1 = fu - (float)iu, wu0 = 1.0f - wu1;
            float fv = (at0[u].y + 1.0f) * 1.5f;
            int iv = (int)fv; iv = iv < 0 ? 0 : (iv > 2 ? 2 : iv);
            const float wv1 = fv - (float)iv, wv0 = 1.0f - wv1;

            bu_[u][0] = iu == 0 ? wu0 : 0.f;
            bu_[u][1] = iu == 0 ? wu1 : (iu == 1 ? wu0 : 0.f);
            bu_[u][2] = iu == 2 ? wu0 : (iu == 1 ? wu1 : 0.f);
            bu_[u][3] = iu == 2 ? wu1 : 0.f;
            const float bv0 = iv == 0 ? wv0 : 0.f;
            const float bv1 = iv == 0 ? wv1 : (iv == 1 ? wv0 : 0.f);
            const float bv2 = iv == 2 ? wv0 : (iv == 1 ? wv1 : 0.f);
            const float bv3 = iv == 2 ? wv1 : 0.f;
            bvE_[u] = hv ? bv1 : bv0;  // m even
            bvO_[u] = hv ? bv3 : bv2;  // m odd
        }

        // ---- 16 MFMAs in 4 independent chains (2 units x even/odd) ----
        f32x4 accE[2] = {{0.f,0.f,0.f,0.f},{0.f,0.f,0.f,0.f}};
        f32x4 accO[2] = {{0.f,0.f,0.f,0.f},{0.f,0.f,0.f,0.f}};
#pragma unroll
        for (int m = 0; m < 8; ++m) {
#pragma unroll
            for (int u = 0; u < 2; ++u) {
                const float t = bu_[u][m >> 1] * ((m & 1) ? bvO_[u] : bvE_[u]);
                union { bf16x8 v; unsigned w[4]; } aa;
                aa.w[0] = pk_bf16(t * xa0[u].x, t * xa0[u].y);
                aa.w[1] = pk_bf16(t * xa0[u].z, t * xa0[u].w);
                aa.w[2] = pk_bf16(t * xb0[u].x, t * xb0[u].y);
                aa.w[3] = pk_bf16(t * xb0[u].z, t * xb0[u].w);
                if (m & 1)
                    accO[u] = __builtin_amdgcn_mfma_f32_16x16x32_bf16(aa.v, bw[m], accO[u], 0, 0, 0);
                else
                    accE[u] = __builtin_amdgcn_mfma_f32_16x16x32_bf16(aa.v, bw[m], accE[u], 0, 0, 0);
            }
        }

        // D layout: row = c*4 + reg (edge in unit), col = lane&15 (out feature)
#pragma unroll
        for (int u = 0; u < 2; ++u) {
            const f32x4 acc = accE[u] + accO[u];
            unsafeAtomicAdd(out + (size_t)r40[u].x * 16 + fo, acc.x);
            unsafeAtomicAdd(out + (size_t)r40[u].y * 16 + fo, acc.y);
            unsafeAtomicAdd(out + (size_t)r40[u].z * 16 + fo, acc.z);
            unsafeAtomicAdd(out + (size_t)r40[u].w * 16 + fo, acc.w);
        }

        // ---- shift pipeline ----
#pragma unroll
        for (int u = 0; u < 2; ++u) {
            at0[u] = at1[u];
            xa0[u] = xa1[u]; xb0[u] = xb1[u];
            col1[u] = col2[u]; at1[u] = at2[u];
        }
    }
}

extern "C" void kernel_launch(void* const* d_in, const int* in_sizes, int n_in,
                              void* d_out, int out_size, void* d_ws, size_t ws_size,
                              hipStream_t stream) {
    const float* x  = (const float*)d_in[0];
    const int*   ei = (const int*)d_in[1];
    const float* ea = (const float*)d_in[2];
    const float* w  = (const float*)d_in[3];
    float* out = (float*)d_out;
    (void)out_size; (void)d_ws; (void)ws_size; (void)in_sizes; (void)n_in;

    zero_out_kernel<<<(OUT_FLOAT4 + 255) / 256, 256, 0, stream>>>((float4*)out);

    const int blocks = N_EDGES / EDGES_PER_BLOCK;  // 3125
    basis_conv_mfma<<<blocks, 256, 0, stream>>>(x, ei, ea, w, out);
}